// Round 16
// baseline (70351.929 us; speedup 1.0000x reference)
//
#include <hip/hip_runtime.h>
#include <hip/hip_bf16.h>

static constexpr int Bb = 32;
static constexpr int Tt = 1024;
static constexpr int Ii = 1024;
static constexpr int Hh = 1024;
static constexpr int NWG = 256;

static constexpr int SLOT_E = Hh * Bb;       // 32768 floats per slot (128 KB)
static constexpr int NS     = 16;            // reused slots: 2 MB, L3-resident

typedef float f4 __attribute__((ext_vector_type(4)));

static constexpr int LDS_WORDS = 36 * 1024;  // R only (partials eliminated)
static constexpr int LDS_BYTES = LDS_WORDS * 4;   // 147456

template <typename PT> __device__ __forceinline__ float pt_to_f(PT v);
template <> __device__ __forceinline__ float pt_to_f<float>(float v) { return v; }
template <> __device__ __forceinline__ float pt_to_f<__hip_bfloat16>(__hip_bfloat16 v) { return __bfloat162float(v); }

template <typename PT> __device__ __forceinline__ PT f_to_pt(float v);
template <> __device__ __forceinline__ float f_to_pt<float>(float v) { return v; }
template <> __device__ __forceinline__ __hip_bfloat16 f_to_pt<__hip_bfloat16>(float v) { return __float2bfloat16(v); }

__device__ __forceinline__ void backoff(int it) {
    if (it < 2)      __builtin_amdgcn_s_sleep(1);
    else if (it < 4) __builtin_amdgcn_s_sleep(2);
    else if (it < 8) __builtin_amdgcn_s_sleep(4);
    else             __builtin_amdgcn_s_sleep(8);
}

// Bypass loads (sc0 sc1): straight from L3 (coherence point of producers'
// write-through stores). Epoch-tag polling self-synchronizes per wave.
#define BGLD(dst, p, lit) \
    asm volatile("global_load_dwordx4 %0, %1, off offset:" lit " sc0 sc1" : "=v"(dst) : "v"(p))
#define BG8(sv, p, a,b,c,d2,e,f,g2,h) \
    BGLD(sv[0],p,a); BGLD(sv[1],p,b); BGLD(sv[2],p,c); BGLD(sv[3],p,d2); \
    BGLD(sv[4],p,e); BGLD(sv[5],p,f); BGLD(sv[6],p,g2); BGLD(sv[7],p,h)
#define VWAIT(n) do { asm volatile("s_waitcnt vmcnt(" #n ")" ::: "memory"); \
                      __builtin_amdgcn_sched_barrier(0); } while (0)

// 2-bit epoch tag in the mantissa LSBs (<=3 ulp). Valid for phase p iff
// (bits & 3) == (p>>4)&3. Init fills tag 3 (matches no early epoch).
__device__ __forceinline__ int grp_tag32(const f4* sv, unsigned texp) {
    int ok = 1;
#pragma unroll
    for (int i = 0; i < 8; ++i)
#pragma unroll
        for (int j = 0; j < 4; ++j)
            ok &= (int)((__float_as_uint(sv[i][j]) & 3u) == texp);
    return ok;
}

#define RETRY32T(sv, texp, p, a,b,c,d2,e,f,g2,h) \
    { int _it = 0; \
      while (!__all(grp_tag32(sv, texp))) { \
          if (_it) backoff(_it); \
          ++_it; \
          BG8(sv, p, a,b,c,d2,e,f,g2,h); \
          VWAIT(0); \
      } }

// ---------------------------------------------------------------------------
// Projection GEMM: P2[g][t][h][b] = (x[b,t,:] @ W_g)[h]   (unchanged)
// ---------------------------------------------------------------------------
template <typename PT>
__global__ __launch_bounds__(256, 2) void proj_gemm(
    const float* __restrict__ X, const float* __restrict__ Wh,
    const float* __restrict__ Wt, const float* __restrict__ Wc,
    PT* __restrict__ P2)
{
    __shared__ float smem[4160];
    float* As = smem;
    float* Bs = smem + 1088;

    const int tid = threadIdx.x;
    const int tx = tid & 15, ty = tid >> 4;
    const int col0 = blockIdx.x * 64;
    const int t0 = blockIdx.y * 2;

    float acc[3][4][4];
#pragma unroll
    for (int g = 0; g < 3; ++g)
#pragma unroll
        for (int mm = 0; mm < 4; ++mm)
#pragma unroll
            for (int nn = 0; nn < 4; ++nn) acc[g][mm][nn] = 0.f;

    const int lm = tid >> 2, lk4 = (tid & 3) * 4;
    const float* aptr = X + ((size_t)(lm & 31) * Tt + (t0 + (lm >> 5))) * Ii + lk4;
    const int bk = tid >> 4, bn4 = (tid & 15) * 4;

    for (int k0 = 0; k0 < Ii; k0 += 16) {
        float4 av = *(const float4*)(aptr + k0);
        As[(lk4 + 0) * 68 + lm] = av.x;
        As[(lk4 + 1) * 68 + lm] = av.y;
        As[(lk4 + 2) * 68 + lm] = av.z;
        As[(lk4 + 3) * 68 + lm] = av.w;
        *(float4*)&Bs[0 * 1024 + bk * 64 + bn4] = *(const float4*)(Wh + (size_t)(k0 + bk) * Hh + col0 + bn4);
        *(float4*)&Bs[1 * 1024 + bk * 64 + bn4] = *(const float4*)(Wt + (size_t)(k0 + bk) * Hh + col0 + bn4);
        *(float4*)&Bs[2 * 1024 + bk * 64 + bn4] = *(const float4*)(Wc + (size_t)(k0 + bk) * Hh + col0 + bn4);
        __syncthreads();
#pragma unroll
        for (int k = 0; k < 16; ++k) {
            float4 a = *(const float4*)&As[k * 68 + ty * 4];
            float a_[4] = {a.x, a.y, a.z, a.w};
#pragma unroll
            for (int g = 0; g < 3; ++g) {
                float4 b = *(const float4*)&Bs[g * 1024 + k * 64 + tx * 4];
                float b_[4] = {b.x, b.y, b.z, b.w};
#pragma unroll
                for (int mm = 0; mm < 4; ++mm)
#pragma unroll
                    for (int nn = 0; nn < 4; ++nn)
                        acc[g][mm][nn] += a_[mm] * b_[nn];
            }
        }
        __syncthreads();
    }

    float* E = smem;
    const int b4 = (tid & 7) * 4;
#pragma unroll 1
    for (int g = 0; g < 3; ++g) {
        __syncthreads();
#pragma unroll
        for (int mm = 0; mm < 4; ++mm)
#pragma unroll
            for (int nn = 0; nn < 4; ++nn)
                E[(ty * 4 + mm) * 65 + tx * 4 + nn] = acc[g][mm][nn];
        __syncthreads();
        PT* dst = P2 + (size_t)g * Tt * Hh * Bb;
#pragma unroll
        for (int it = 0; it < 4; ++it) {
            const int line = (tid >> 3) + it * 32;
            const int tt = line >> 6, hh = line & 63;
            const float o0 = E[(tt * 32 + b4 + 0) * 65 + hh];
            const float o1 = E[(tt * 32 + b4 + 1) * 65 + hh];
            const float o2v = E[(tt * 32 + b4 + 2) * 65 + hh];
            const float o3 = E[(tt * 32 + b4 + 3) * 65 + hh];
            PT* d = dst + ((size_t)(t0 + tt) * Hh + col0 + hh) * Bb + b4;
            d[0] = f_to_pt<PT>(o0); d[1] = f_to_pt<PT>(o1);
            d[2] = f_to_pt<PT>(o2v); d[3] = f_to_pt<PT>(o3);
        }
    }
}

// ---------------------------------------------------------------------------
// init: slot 0 <- s0 transposed [h][b] (tag 0); slots 1..NS-1 <- tag-3 fill.
// ---------------------------------------------------------------------------
__global__ __launch_bounds__(256) void init_ring_s(const float* __restrict__ s0,
                                                   float* __restrict__ ring)
{
    const size_t tid = (size_t)blockIdx.x * 256 + threadIdx.x;
    if (tid < (size_t)Bb * Hh) {
        const int b = (int)(tid >> 10), h = (int)(tid & 1023);
        ring[h * 32 + b] = __uint_as_float(__float_as_uint(s0[tid]) & ~3u);
    }
    const uint4 pat = {3u, 3u, 3u, 3u};
    uint4* base = (uint4*)(ring + SLOT_E);
    const size_t n16 = (size_t)(NS - 1) * SLOT_E * 4 / 16;
    const size_t stride = (size_t)gridDim.x * 256;
    for (size_t i = tid; i < n16; i += stride) base[i] = pat;
}

// ---------------------------------------------------------------------------
// out transpose from fp32 shist [t][h][b] -> out[b][t][h]; t==T-1 also -> sT.
// ---------------------------------------------------------------------------
__global__ __launch_bounds__(256) void out_transpose_hist(
    const float* __restrict__ shist, float* __restrict__ out, float* __restrict__ sT)
{
    __shared__ float tile[128 * 33];
    const int tid = threadIdx.x;
    const int h0 = blockIdx.x * 128;
    const int t = blockIdx.y;
    const float* src = shist + ((size_t)t * Hh + h0) * Bb;
#pragma unroll
    for (int e = 0; e < 16; ++e) {
        const int idx = e * 256 + tid;
        tile[(idx >> 5) * 33 + (idx & 31)] = src[idx];
    }
    __syncthreads();
    const int hi = tid & 31, bq = tid >> 5;
#pragma unroll
    for (int e = 0; e < 4; ++e) {
        const int b = bq + e * 8;
        float4 v;
        v.x = tile[(hi * 4 + 0) * 33 + b];
        v.y = tile[(hi * 4 + 1) * 33 + b];
        v.z = tile[(hi * 4 + 2) * 33 + b];
        v.w = tile[(hi * 4 + 3) * 33 + b];
        *(float4*)(out + ((size_t)b * Tt + t) * Hh + h0 + hi * 4) = v;
        if (t == Tt - 1) *(float4*)(sT + (size_t)b * Hh + h0 + hi * 4) = v;
    }
}

// ---------------------------------------------------------------------------
// WAVE-AUTONOMOUS dataflow recurrence: zero intra-WG synchronization in the
// loop. Wave w owns batches w*8..w*8+7 and computes ALL 12 gate-rows for
// them: lane = ks(32 k-slices, bits 1-5) x bq(2 batch-quads, bit 0).
// K-reduce = 5-level in-wave shfl_xor allreduce (no LDS partials, no
// __syncthreads). Output mapping puts each lane's (q,b) sums in its own
// registers. Waves slip freely -> one wave's tag-retry wait overlaps the
// other three waves' FMAs on their own SIMDs (cross-wave latency hiding).
// Ring: 16 reused L3-hot slots + 2-bit epoch tags (r15-proven).
// ---------------------------------------------------------------------------
template <typename PT>
__global__ __launch_bounds__(256, 1) void rhn_recur(
    const float* __restrict__ Rh, const float* __restrict__ Rt,
    const float* __restrict__ Rc, const float* __restrict__ bh,
    const float* __restrict__ bt, const float* __restrict__ bc,
    const PT* __restrict__ P2, float* __restrict__ ring,
    float* __restrict__ shist, const float* __restrict__ s0in)
{
    extern __shared__ float lds[];

    const int g = blockIdx.x;
    const int tid = threadIdx.x;

    {   // load R rows, swizzle word = j*1024 + (k ^ (((k>>5)&7)<<2))
        const int k4 = tid * 4;
        const int sk = k4 ^ (((k4 >> 5) & 7) << 2);
#pragma unroll 1
        for (int j = 0; j < 36; ++j) {
            const int l = j / 12;
            const int rem = j - l * 12;
            const int gt = rem >> 2;
            const int q = rem & 3;
            const int h = (q << 8) | g;
            const float* src = (gt == 0 ? Rh : (gt == 1 ? Rt : Rc)) + ((size_t)l * Hh + h) * Hh;
            *(float4*)&lds[(j << 10) | sk] = *(const float4*)(src + k4);
        }
    }
    __syncthreads();   // R ready; ONLY sync in the kernel

    const int w    = tid >> 6;            // wave id -> batch octet
    const int lane = tid & 63;
    const int ksp  = lane >> 1;           // 0..31 k-slice (32 k each)
    const int bq   = lane & 1;            // batch quad within octet
    const int q8   = ksp & 7;
    const int bb   = w * 8 + bq * 4;      // first batch of this lane's f4

    // output mapping (lane < 32): q = (lane>>1)&3, own bq = lane&1 (matches
    // the reduced data this lane holds), element = lane>>3.
    const int oq  = (lane >> 1) & 3;
    const int obe = lane >> 3;            // 0..3
    const int ob  = w * 8 + (lane & 1) * 4 + obe;
    const int oh  = (oq << 8) | g;

    int o2[8];
#pragma unroll
    for (int c = 0; c < 8; ++c) o2[c] = ((c ^ q8) << 2);

    float brh[3], brt[3], brc[3];
    if (lane < 32) {
#pragma unroll
        for (int l = 0; l < 3; ++l) {
            brh[l] = bh[l * Hh + oh];
            brt[l] = bt[l * Hh + oh];
            brc[l] = bc[l * Hh + oh];
        }
    }

    float so_reg = (lane < 32) ? s0in[(size_t)ob * Hh + oh] : 0.f;

#pragma unroll 1
    for (int t = 0; t < Tt; ++t) {
#pragma unroll 1
        for (int l = 0; l < 3; ++l) {
            const int p = t * 3 + l;
            const int slr = p & (NS - 1);
            const unsigned texp = (unsigned)((p >> 4) & 3);
            const int slw = (p + 1) & (NS - 1);
            const unsigned twr = (unsigned)(((p + 1) >> 4) & 3);

            float pv0 = 0.f, pv1 = 0.f, pv2 = 0.f;
            if (l == 0 && lane < 32) {
                const size_t pb = ((size_t)t * Hh + oh) * Bb + ob;
                pv0 = pt_to_f<PT>(P2[pb]);
                pv1 = pt_to_f<PT>(P2[(size_t)Tt * Hh * Bb + pb]);
                pv2 = pt_to_f<PT>(P2[2 * (size_t)Tt * Hh * Bb + pb]);
            }

            const float* rp = lds + l * 12288 + (ksp << 5);
            const float* sA = ring + (size_t)slr * SLOT_E + (size_t)ksp * 1024 + bb;

            f4 accv[12];
#pragma unroll
            for (int jj = 0; jj < 12; ++jj) accv[jj] = (f4){0.f, 0.f, 0.f, 0.f};

            f4 sv0[8], sv1[8];
            BG8(sv0, sA, "0","128","256","384","512","640","768","896");
            BG8(sv1, sA, "1024","1152","1280","1408","1536","1664","1792","1920");
            VWAIT(8);
            RETRY32T(sv0, texp, sA, "0","128","256","384","512","640","768","896");
#pragma unroll
            for (int jj = 0; jj < 12; ++jj) {
                const f4 r0 = *(const f4*)(rp + jj * 1024 + o2[0]);
                const f4 r1 = *(const f4*)(rp + jj * 1024 + o2[1]);
                f4 a = accv[jj];
                a += sv0[0] * r0[0]; a += sv0[1] * r0[1]; a += sv0[2] * r0[2]; a += sv0[3] * r0[3];
                a += sv0[4] * r1[0]; a += sv0[5] * r1[1]; a += sv0[6] * r1[2]; a += sv0[7] * r1[3];
                accv[jj] = a;
            }
            BG8(sv0, sA, "2048","2176","2304","2432","2560","2688","2816","2944");
            VWAIT(8);
            RETRY32T(sv1, texp, sA, "1024","1152","1280","1408","1536","1664","1792","1920");
#pragma unroll
            for (int jj = 0; jj < 12; ++jj) {
                const f4 r0 = *(const f4*)(rp + jj * 1024 + o2[2]);
                const f4 r1 = *(const f4*)(rp + jj * 1024 + o2[3]);
                f4 a = accv[jj];
                a += sv1[0] * r0[0]; a += sv1[1] * r0[1]; a += sv1[2] * r0[2]; a += sv1[3] * r0[3];
                a += sv1[4] * r1[0]; a += sv1[5] * r1[1]; a += sv1[6] * r1[2]; a += sv1[7] * r1[3];
                accv[jj] = a;
            }
            BG8(sv1, sA, "3072","3200","3328","3456","3584","3712","3840","3968");
            VWAIT(8);
            RETRY32T(sv0, texp, sA, "2048","2176","2304","2432","2560","2688","2816","2944");
#pragma unroll
            for (int jj = 0; jj < 12; ++jj) {
                const f4 r0 = *(const f4*)(rp + jj * 1024 + o2[4]);
                const f4 r1 = *(const f4*)(rp + jj * 1024 + o2[5]);
                f4 a = accv[jj];
                a += sv0[0] * r0[0]; a += sv0[1] * r0[1]; a += sv0[2] * r0[2]; a += sv0[3] * r0[3];
                a += sv0[4] * r1[0]; a += sv0[5] * r1[1]; a += sv0[6] * r1[2]; a += sv0[7] * r1[3];
                accv[jj] = a;
            }
            VWAIT(0);
            RETRY32T(sv1, texp, sA, "3072","3200","3328","3456","3584","3712","3840","3968");
#pragma unroll
            for (int jj = 0; jj < 12; ++jj) {
                const f4 r0 = *(const f4*)(rp + jj * 1024 + o2[6]);
                const f4 r1 = *(const f4*)(rp + jj * 1024 + o2[7]);
                f4 a = accv[jj];
                a += sv1[0] * r0[0]; a += sv1[1] * r0[1]; a += sv1[2] * r0[2]; a += sv1[3] * r0[3];
                a += sv1[4] * r1[0]; a += sv1[5] * r1[1]; a += sv1[6] * r1[2]; a += sv1[7] * r1[3];
                accv[jj] = a;
            }

            // in-wave K allreduce over ks (lane bits 1..5)
#pragma unroll
            for (int jj = 0; jj < 12; ++jj) {
#pragma unroll
                for (int st = 2; st <= 32; st <<= 1) {
                    accv[jj][0] += __shfl_xor(accv[jj][0], st);
                    accv[jj][1] += __shfl_xor(accv[jj][1], st);
                    accv[jj][2] += __shfl_xor(accv[jj][2], st);
                    accv[jj][3] += __shfl_xor(accv[jj][3], st);
                }
            }

            if (lane < 32) {
                float vals[3];
#pragma unroll
                for (int gt = 0; gt < 3; ++gt) {
                    const f4 v = accv[gt * 4 + oq];
                    const float e01 = (obe & 1) ? v[1] : v[0];
                    const float e23 = (obe & 1) ? v[3] : v[2];
                    vals[gt] = (obe & 2) ? e23 : e01;
                }
                float bb0, bb1, bb2;
                if (l == 0)      { bb0 = brh[0]; bb1 = brt[0]; bb2 = brc[0]; }
                else if (l == 1) { bb0 = brh[1]; bb1 = brt[1]; bb2 = brc[1]; }
                else             { bb0 = brh[2]; bb1 = brt[2]; bb2 = brc[2]; }
                vals[0] += bb0; vals[1] += bb1; vals[2] += bb2;
                if (l == 0) { vals[0] += pv0; vals[1] += pv1; vals[2] += pv2; }
                const float hv = 1.f - 2.f / (1.f + __expf(2.f * vals[0]));
                const float tv = 1.f / (1.f + __expf(-vals[1]));
                const float cv = 1.f / (1.f + __expf(-vals[2]));
                const float sn = hv * tv + so_reg * cv;
                so_reg = sn;
                const unsigned bits = (__float_as_uint(sn) & ~3u) | twr;
                __hip_atomic_store((unsigned*)(ring + (size_t)slw * SLOT_E + oh * 32 + ob),
                                   bits, __ATOMIC_RELAXED, __HIP_MEMORY_SCOPE_AGENT);
                if (l == 2)
                    shist[((size_t)t * Hh + oh) * Bb + ob] = sn;
            }
        }
    }
}

// ---------------------------------------------------------------------------
template <typename PT>
static void launch_recur(const float* Rh, const float* Rt, const float* Rc,
                         const float* bh, const float* bt, const float* bc,
                         const PT* P2, float* ring, float* shist,
                         const float* s0, hipStream_t stream)
{
    (void)hipFuncSetAttribute(reinterpret_cast<const void*>(rhn_recur<PT>),
                              hipFuncAttributeMaxDynamicSharedMemorySize, LDS_BYTES);
    void* args[] = {(void*)&Rh, (void*)&Rt, (void*)&Rc, (void*)&bh, (void*)&bt, (void*)&bc,
                    (void*)&P2, (void*)&ring, (void*)&shist, (void*)&s0};
    hipError_t e = hipLaunchCooperativeKernel(reinterpret_cast<void*>(rhn_recur<PT>),
                                              dim3(NWG), dim3(256), args, LDS_BYTES, stream);
    if (e != hipSuccess) {
        // Fallback: plain launch. 256 blocks x 1/CU on 256 CUs -> co-resident.
        rhn_recur<PT><<<dim3(NWG), dim3(256), LDS_BYTES, stream>>>(
            Rh, Rt, Rc, bh, bt, bc, P2, ring, shist, s0);
    }
}

extern "C" void kernel_launch(void* const* d_in, const int* in_sizes, int n_in,
                              void* d_out, int out_size, void* d_ws, size_t ws_size,
                              hipStream_t stream)
{
    (void)in_sizes; (void)n_in; (void)out_size;
    const float* x  = (const float*)d_in[0];
    const float* s0 = (const float*)d_in[1];
    const float* wh = (const float*)d_in[2];
    const float* wt = (const float*)d_in[3];
    const float* wc = (const float*)d_in[4];
    const float* Rh = (const float*)d_in[5];
    const float* Rt = (const float*)d_in[6];
    const float* Rc = (const float*)d_in[7];
    const float* bh = (const float*)d_in[8];
    const float* bt = (const float*)d_in[9];
    const float* bc = (const float*)d_in[10];

    float* out = (float*)d_out;
    float* sT  = out + (size_t)Bb * Tt * Hh;

    const size_t THB   = (size_t)Tt * Hh * Bb;
    const size_t p2f   = 3 * THB * 4, p2h = 3 * THB * 2;
    const size_t ringS = (size_t)NS * SLOT_E * 4;   // 2 MB
    const size_t shF   = THB * 4;                   // 128 MB

    char* w = (char*)d_ws;

    if (ws_size >= p2f + ringS + shF + 4096) {
        // tier A: fp32 P2
        float* P2 = (float*)w;
        float* ring = (float*)(w + p2f);
        float* shist = (float*)(w + p2f + ringS);
        proj_gemm<float><<<dim3(16, 512), 256, 0, stream>>>(x, wh, wt, wc, P2);
        init_ring_s<<<128, 256, 0, stream>>>(s0, ring);
        launch_recur<float>(Rh, Rt, Rc, bh, bt, bc, P2, ring, shist, s0, stream);
        out_transpose_hist<<<dim3(8, 1024), 256, 0, stream>>>(shist, out, sT);
    } else {
        // tier B: bf16 P2 (ring + shist stay fp32)
        __hip_bfloat16* P2 = (__hip_bfloat16*)w;
        float* ring = (float*)(w + p2h);
        float* shist = (float*)(w + p2h + ringS);
        proj_gemm<__hip_bfloat16><<<dim3(16, 512), 256, 0, stream>>>(x, wh, wt, wc, P2);
        init_ring_s<<<128, 256, 0, stream>>>(s0, ring);
        launch_recur<__hip_bfloat16>(Rh, Rt, Rc, bh, bt, bc, P2, ring, shist, s0, stream);
        out_transpose_hist<<<dim3(8, 1024), 256, 0, stream>>>(shist, out, sT);
    }
}